// Round 8
// baseline (178.429 us; speedup 1.0000x reference)
//
#include <hip/hip_runtime.h>

// SNN spike layer: causal alpha-PSP FIR conv (taps 1..76; srm[0]==0 exactly)
// + sequential refractory threshold scan.
//
// Round-8: the 7-round ledger shows the register allocator lands at 84-96
// VGPR no matter the live set (R0:96/~165 live, R4:84/~145, R7:88/~100),
// spilling the rest (~26-44 MiB scratch leak visible in WRITE_SIZE). Root
// cause: __launch_bounds__ only sets MIN waves/EU; the allocator's default
// occupancy TARGET (~5 waves/EU ~= 96 VGPR) makes it spill "cold" values
// rather than use more registers. Our occupancy is grid-limited to 1
// wave/SIMD (65536 threads = 1024 waves = 1024 SIMDs), so the spills buy
// nothing. Fix: amdgpu_waves_per_eu(1,1) sets the allocator's target to
// 1 wave/EU -> full 512-VGPR budget, no spill incentive.
// Body = round-1's verified kernel (fewest insts/chunk: no pack/unpack tax)
// + sched_barrier(0) pinning the prefetch above the conv (round-2 lesson:
// under pressure the scheduler sinks the loads below the conv).
//
// Bit-exactness invariant (absmax must stay 0.0): each u[t] accumulates taps
// j=1..76 ascending via a single fmaf chain (srm[0]==0 dropped: fmaf(0,x,u)
// ==u for finite x); pre-window zeros are fmaf(w,0,u) no-ops; scan step
// identical to the verified baseline. No reassociation anywhere.

#define T_LEN 300
#define CH 20
#define NCHUNK 15          // 15 * 20 == 300 exactly
#define KS 77              // srm kernel length (alpha, tau=10, eps_tol=0.01)
#define KT 76              // effective taps: j = 1..76 (srm[0] == 0 exactly)
#define WIN 96             // hist window: s[t0-76 .. t0+19]
#define KR 10              // ref kernel tail length (K_ref=11 -> 10 pending)
#define THETA_V 10.0f

__global__ __launch_bounds__(256)
__attribute__((amdgpu_waves_per_eu(1, 1)))
void spike_layer_kernel(
    const float* __restrict__ spike_in,
    const float* __restrict__ srm, int srm_len,
    const float* __restrict__ refk, int ref_len,
    float* __restrict__ out, int B)
{
    int b = blockIdx.x * blockDim.x + threadIdx.x;
    if (b >= B) return;

    const float* row  = spike_in + (size_t)b * T_LEN;
    float*       orow = out      + (size_t)b * T_LEN;

    // srm taps (uniform-address loads -> s_load into SGPRs; SGPR_Count=112
    // across all rounds confirms taps+rt scalarize). Tap 0 skipped: exactly 0.
    float srm_r[KS];
#pragma unroll
    for (int i = 1; i < KS; ++i) srm_r[i] = (i < srm_len) ? srm[i] : 0.0f;

    // refractory tail: ref_kernel[1..], contributions to t+1..t+KR
    float rt[KR];
#pragma unroll
    for (int i = 0; i < KR; ++i) rt[i] = (i + 1 < ref_len) ? refk[i + 1] : 0.0f;

    // history window: hist[i] = s[t0 + i - KT]; hist[KT..KT+CH-1] = current chunk
    float hist[WIN];
#pragma unroll
    for (int i = 0; i < WIN - CH; ++i) hist[i] = 0.0f;   // t < 0 -> no spikes

    // pending refractory contributions, circular: logical pend[i] at
    // pend[(r+i)%KR] with r = t%KR (compile-time: CH == 2*KR).
    float pend[KR];
#pragma unroll
    for (int i = 0; i < KR; ++i) pend[i] = 0.0f;

    // preload chunk 0
    float nxt[CH];
    {
        const float4* p = (const float4*)row;
#pragma unroll
        for (int i = 0; i < CH / 4; ++i) {
            float4 v = p[i];
            nxt[4*i+0] = v.x; nxt[4*i+1] = v.y; nxt[4*i+2] = v.z; nxt[4*i+3] = v.w;
        }
    }

#pragma unroll 1           // keep the ~1.7k-inst body I-cache resident
    for (int ch = 0; ch < NCHUNK; ++ch) {
        // install current chunk into window tail
#pragma unroll
        for (int i = 0; i < CH; ++i) hist[WIN - CH + i] = nxt[i];

        // prefetch next chunk; sched_barrier pins the load ISSUE here so the
        // latency hides under the 1520-FMA conv (round-2 evidence: the
        // scheduler otherwise sinks these loads below the conv).
        if (ch + 1 < NCHUNK) {
            const float4* p = (const float4*)(row + (ch + 1) * CH);
#pragma unroll
            for (int i = 0; i < CH / 4; ++i) {
                float4 v = p[i];
                nxt[4*i+0] = v.x; nxt[4*i+1] = v.y; nxt[4*i+2] = v.z; nxt[4*i+3] = v.w;
            }
        }
        __builtin_amdgcn_sched_barrier(0);

        // conv: u[t0+c] = sum_{j=1}^{76} srm[j] * s[t0+c-j]; 20 indep chains
        float u[CH];
#pragma unroll
        for (int c = 0; c < CH; ++c) u[c] = 0.0f;
#pragma unroll
        for (int j = 1; j < KS; ++j) {
            const float w = srm_r[j];
#pragma unroll
            for (int c = 0; c < CH; ++c)
                u[c] = fmaf(w, hist[KT + c - j], u[c]);
        }

        // sequential threshold scan; circular pending queue
        float so[CH];
#pragma unroll
        for (int c = 0; c < CH; ++c) {
            const int r = c % KR;      // compile-time
            float u_eff = u[c] + pend[r];
            float s = (u_eff >= THETA_V) ? 1.0f : 0.0f;
#pragma unroll
            for (int i = 0; i < KR - 1; ++i)
                pend[(r + 1 + i) % KR] = fmaf(s, rt[i], pend[(r + 1 + i) % KR]);
            pend[r] = s * rt[KR - 1];  // consumed slot becomes logical tail
            so[c] = s;                 // s / TS, TS == 1
        }

        // store chunk
        {
            float4* op = (float4*)(orow + ch * CH);
#pragma unroll
            for (int i = 0; i < CH / 4; ++i) {
                float4 v;
                v.x = so[4*i+0]; v.y = so[4*i+1]; v.z = so[4*i+2]; v.w = so[4*i+3];
                op[i] = v;
            }
        }

        // slide window by CH
#pragma unroll
        for (int i = 0; i < WIN - CH; ++i) hist[i] = hist[i + CH];
    }
}

extern "C" void kernel_launch(void* const* d_in, const int* in_sizes, int n_in,
                              void* d_out, int out_size, void* d_ws, size_t ws_size,
                              hipStream_t stream) {
    const float* spike_in = (const float*)d_in[0];
    const float* srm      = (const float*)d_in[1];
    const float* refk     = (const float*)d_in[2];
    float* out = (float*)d_out;

    int srm_len = in_sizes[1];
    int ref_len = in_sizes[2];
    int B = in_sizes[0] / T_LEN;   // 65536 neurons

    int block = 256;
    int grid = (B + block - 1) / block;
    spike_layer_kernel<<<grid, block, 0, stream>>>(spike_in, srm, srm_len,
                                                   refk, ref_len, out, B);
}